// Round 8
// baseline (203.346 us; speedup 1.0000x reference)
//
#include <hip/hip_runtime.h>
#include <hip/hip_bf16.h>

#define C_IN  64
#define C_OUT 128
#define KK    27
#define HH    100000
#define TB    1563         // transpose blocks = ceil(HH/64)
#define WB    108          // weight-convert blocks (108*2048 = 221184 elems)
#define NBLK  782          // ceil(HH/128)

typedef __attribute__((ext_vector_type(8)))  short s8v;    // 8 bf16 (MFMA A/B frag, 4 VGPRs)
typedef __attribute__((ext_vector_type(16))) float f32x16; // 32x32 MFMA C/D frag

// Non-draining pipeline barrier: s_waitcnt vmcnt(8) lgkmcnt(0); s_barrier.
// simm16: vmcnt[3:0]=8, expcnt=7 (ignored), lgkmcnt=0 -> 0x0078.
// Retires the 8 oldest outstanding VMEM ops (the W DMAs) while leaving the 8
// B-gather prefetches in flight ACROSS the barrier.
#define PIPE_BARRIER() do { \
    __asm__ __volatile__("" ::: "memory"); \
    __builtin_amdgcn_s_waitcnt(0x0078); \
    __builtin_amdgcn_s_barrier(); \
    __asm__ __volatile__("" ::: "memory"); \
} while (0)

#define ISSUE_FENCE() __asm__ __volatile__("" ::: "memory")

__device__ inline unsigned short f2bf(float f) {
    __hip_bfloat16 h = __float2bfloat16(f);
    return *reinterpret_cast<unsigned short*>(&h);
}

__device__ inline void dma16(const void* g, void* l) {
    __builtin_amdgcn_global_load_lds((const __attribute__((address_space(1))) void*)g,
                                     (__attribute__((address_space(3))) void*)l, 16, 0, 0);
}

// ---- prep: transpose x -> xt (bf16, [h][64]), W -> wk (bf16, [k][o][64] XOR-swizzled) ----
// wk physical 16B-chunk pj of row o holds logical chunk pj ^ (o&7).
__global__ __launch_bounds__(256) void prep_kernel(const float* __restrict__ x,
                                                   const float* __restrict__ w,
                                                   unsigned short* __restrict__ xt,
                                                   unsigned short* __restrict__ wk) {
    const int tid = threadIdx.x;
    if (blockIdx.x < TB) {
        __shared__ __align__(16) unsigned short ts[64 * 72];
        const int hbase = blockIdx.x * 64;
        #pragma unroll
        for (int it = 0; it < 16; ++it) {
            int i = it * 256 + tid;           // 64h x 64c
            int c = i >> 6, hl = i & 63;
            int hg = hbase + hl;
            float v = (hg < HH) ? x[(size_t)c * HH + hg] : 0.f;  // coalesced in h
            ts[hl * 72 + c] = f2bf(v);
        }
        __syncthreads();
        #pragma unroll
        for (int it = 0; it < 2; ++it) {
            int u = it * 256 + tid;           // 64 rows x 8 chunks of 16B
            int hl = u >> 3, part = u & 7;
            int hg = hbase + hl;
            if (hg < HH)
                *(int4*)&xt[(size_t)hg * 64 + part * 8] = *(const int4*)&ts[hl * 72 + part * 8];
        }
    } else {
        int b = blockIdx.x - TB;
        int base = b * 2048 + tid;
        #pragma unroll
        for (int j = 0; j < 8; ++j) {
            int t = base + j * 256;           // wk index: t = k*8192 + o*64 + jj
            int jj = t & 63, o = (t >> 6) & 127, kx = t >> 13;
            int lc = (jj >> 3) ^ (o & 7);     // logical chunk
            int c  = lc * 8 + (jj & 7);
            wk[t] = f2bf(w[(size_t)o * (C_IN * KK) + c * KK + kx]);
        }
    }
}

// ---------------- main gather-GEMM: 32x32x16 MFMA, high A-reuse ----------------
// block 128 thr = 2 waves; wave tile M=128 (all o) x N=64 h (nt=2 of 32).
// A (weights): async-DMA double-buffered LDS, read as 32x32 frags (2x MACs per LDS byte
// vs 16x16). B: direct global->VGPR gathers, ping-pong, surviving barriers via vmcnt(8).
__global__ __launch_bounds__(128, 2) void conv_main(const unsigned short* __restrict__ xt,
                                                    const unsigned short* __restrict__ wk,
                                                    const int* __restrict__ neigh,
                                                    float* __restrict__ out) {
    __shared__ int neigh_s[128 * KK];                            // 13824 B, [h][k]
    __shared__ __align__(16) unsigned short w_s[2][128 * 64];    // 2 x 16 KB, XOR-swizzled rows

    const int tid  = threadIdx.x;
    const int wave = tid >> 6;
    const int lane = tid & 63;
    const int l31  = lane & 31;
    const int hi   = lane >> 5;          // k-group: holds k-halves [hi*8, hi*8+8) of each 16-chunk
    const int hbase = blockIdx.x * 128;

    // ---- stage neighbor indices (coalesced; 27*128 = 3456 exactly) ----
    #pragma unroll
    for (int j = 0; j < KK; ++j) {
        int i = j * 128 + tid;
        int hl = i / KK, kx = i - hl * KK;
        int hg = hbase + hl;
        neigh_s[i] = (hg < HH) ? neigh[(size_t)hg * KK + kx] : -1;
    }

    // ---- W DMA: 16 KB slice k -> w_s[b]; 8 insts/thread, lane-contiguous ----
    auto dmaW = [&](int k, int b) {
        const unsigned short* src = wk + (size_t)k * (C_OUT * C_IN) + wave * 4096 + lane * 8;
        unsigned short* dst = &w_s[b][wave * 4096 + lane * 8];
        #pragma unroll
        for (int i = 0; i < 8; ++i)
            dma16(src + i * 512, dst + i * 512);   // 8 rows (1 KB) per inst per wave
    };

    dmaW(0, 0);

    f32x16 acc[4][2];
    #pragma unroll
    for (int mt = 0; mt < 4; ++mt)
        #pragma unroll
        for (int nt = 0; nt < 2; ++nt)
            #pragma unroll
            for (int r = 0; r < 16; ++r)
                acc[mt][nt][r] = 0.f;

    __syncthreads();   // once: neigh_s visible + DMA(0) drained (full drain OK here)

    // ---- B loader: lane covers col n, c in {hi*8 + kc*16 .. +8} for kc=0..3 ----
    const int nrow0 = (wave * 64 + l31) * KK;       // neigh_s row offset, nt=0
    auto loadB = [&](int kk, int4 (&B)[2][4]) {
        #pragma unroll
        for (int nt = 0; nt < 2; ++nt) {
            int idx = neigh_s[nrow0 + nt * (32 * KK) + kk];
            if (idx >= 0) {
                const unsigned short* base = xt + (size_t)idx * 64 + hi * 8;
                #pragma unroll
                for (int kc = 0; kc < 4; ++kc)
                    B[nt][kc] = *(const int4*)(base + kc * 16);
            } else {
                #pragma unroll
                for (int kc = 0; kc < 4; ++kc)
                    B[nt][kc] = make_int4(0, 0, 0, 0);
            }
        }
    };

    auto mfma_phase = [&](const unsigned short* wbuf, int4 (&B)[2][4]) {
        #pragma unroll
        for (int kc = 0; kc < 4; ++kc) {
            #pragma unroll
            for (int mt = 0; mt < 4; ++mt) {
                int row = mt * 32 + l31;
                int pc = (hi + 2 * kc) ^ (l31 & 7);       // XOR-swizzled physical chunk
                s8v a = *(const s8v*)&wbuf[row * 64 + pc * 8];
                acc[mt][0] = __builtin_amdgcn_mfma_f32_32x32x16_bf16(
                    a, __builtin_bit_cast(s8v, B[0][kc]), acc[mt][0], 0, 0, 0);
                acc[mt][1] = __builtin_amdgcn_mfma_f32_32x32x16_bf16(
                    a, __builtin_bit_cast(s8v, B[1][kc]), acc[mt][1], 0, 0, 0);
            }
        }
    };

    int4 B0[2][4], B1[2][4];
    loadB(0, B0);

    // 27 = 13*2 + 1; ping-pong (B0,buf0)/(B1,buf1); all load counts static -> exact vmcnt math
    #pragma unroll 1
    for (int kb = 0; kb < 13; ++kb) {
        int k = kb * 2;
        dmaW(k + 1, 1);                  // 8 DMA (oldest in VMEM queue)
        ISSUE_FENCE();
        loadB(k + 1, B1);                // 8 gathers (survive the barrier)
        mfma_phase(w_s[0], B0);          // compiler waits only on B0's gathers
        PIPE_BARRIER();                  // vmcnt(8): DMA k+1 retired, B(k+1) still flying

        dmaW(k + 2, 0);                  // k+2 <= 26 always
        ISSUE_FENCE();
        loadB(k + 2, B0);
        mfma_phase(w_s[1], B1);
        PIPE_BARRIER();                  // vmcnt(8): DMA k+2 retired, B(k+2) still flying
    }
    mfma_phase(w_s[0], B0);              // k = 26

    // ---- epilogue: 32x32 C/D: o = mt*32 + (r&3) + 8*(r>>2) + 4*hi; h = nt*32 + l31 ----
    #pragma unroll
    for (int mt = 0; mt < 4; ++mt) {
        #pragma unroll
        for (int nt = 0; nt < 2; ++nt) {
            int hg = hbase + wave * 64 + nt * 32 + l31;
            if (hg < HH) {
                #pragma unroll
                for (int r = 0; r < 16; ++r) {
                    int o = mt * 32 + (r & 3) + 8 * (r >> 2) + 4 * hi;
                    float v = acc[mt][nt][r];
                    out[(size_t)o * HH + hg] = v > 0.f ? v : 0.f;
                }
            }
        }
    }
}

extern "C" void kernel_launch(void* const* d_in, const int* in_sizes, int n_in,
                              void* d_out, int out_size, void* d_ws, size_t ws_size,
                              hipStream_t stream) {
    const float* data_in = (const float*)d_in[0];
    const int*   neigh   = (const int*)d_in[1];
    const float* weight  = (const float*)d_in[2];
    float* out = (float*)d_out;

    unsigned short* xt = (unsigned short*)d_ws;            // H*64 bf16 = 12.8 MB
    unsigned short* wk = xt + (size_t)HH * 64;             // 27*128*64 bf16 = 442 KB

    prep_kernel<<<TB + WB, 256, 0, stream>>>(data_in, weight, xt, wk);
    conv_main<<<NBLK, 128, 0, stream>>>(xt, wk, neigh, out);
}